// Round 1
// baseline (571.621 us; speedup 1.0000x reference)
//
#include <hip/hip_runtime.h>
#include <hip/hip_bf16.h>

#define SQ2 0.70710678118654752440f

typedef __attribute__((ext_vector_type(4))) float f32x4;
typedef __attribute__((ext_vector_type(8))) short s16x8;

// B=16, Cin=256, H=W=64.  rimg channels = 512 (0..255 = branch0, 256..511 = x identity)

__device__ __forceinline__ unsigned short f2bf(float f){
  unsigned u = __builtin_bit_cast(unsigned, f);
  u += 0x7FFFu + ((u >> 16) & 1u);
  return (unsigned short)(u >> 16);
}

// ---------------- weight converts ----------------
__global__ void k_cvt_cw(const float* __restrict__ w, unsigned short* __restrict__ o){
  int g = blockIdx.x * blockDim.x + threadIdx.x;
  if (g < 256*256) o[g] = f2bf(w[g]);
}

// convW_w [o=256][cin=512][kh=3][kw=3] f32  ->  Wb [tap=kh*3+kw][o][cin] bf16
__global__ void k_cvt_wb(const float* __restrict__ w, unsigned short* __restrict__ o){
  const int N = 256*512*9;
  for (int g = blockIdx.x*blockDim.x + threadIdx.x; g < N; g += gridDim.x*blockDim.x){
    int tap = g % 9;
    int t2  = g / 9;
    int cin = t2 & 511;
    int oc  = t2 >> 9;
    o[(tap*256 + oc)*512 + cin] = f2bf(w[g]);
  }
}

// ---------------- x (NCHW f32) -> Cb NHWC bf16, channels 256..511 ----------------
__global__ __launch_bounds__(256) void k_x_nhwc(const float* __restrict__ x,
                                                unsigned short* __restrict__ Cb){
  __shared__ float tile[32][65];
  int bh = blockIdx.x;            // b*64 + h
  int b = bh >> 6, h = bh & 63;
  int t = threadIdx.x;
  for (int cc = 0; cc < 256; cc += 32){
    int w = t & 63, c4 = t >> 6;
#pragma unroll
    for (int r = 0; r < 8; ++r){
      int c = c4*8 + r;
      tile[c][w] = x[((b*256 + cc + c)*64 + h)*64 + w];
    }
    __syncthreads();
    int c = t & 31, w4 = t >> 5;
#pragma unroll
    for (int r = 0; r < 8; ++r){
      int w2 = w4*8 + r;
      Cb[((b*64 + h)*64 + w2)*512 + 256 + cc + c] = f2bf(tile[c][w2]);
    }
    __syncthreads();
  }
}

// ---------------- fused 1x1 conv (bf16 MFMA) + Haar DWT -> subbands f32 ----------------
// subbands layout: [s=0(A),1(H),2(V),3(D)][b=16][i=32][j=32][o=256] f32 (lives in d_out)
__global__ __launch_bounds__(256) void k_gemm1_dwt(const unsigned short* __restrict__ Cb,
                                                   const unsigned short* __restrict__ cw,
                                                   float* __restrict__ sub){
  int bx = blockIdx.x;                     // 2048 = 16b * 32rowpair * 4otile
  int ot = bx & 3, rp = (bx >> 2) & 31, b = bx >> 7;
  int tid = threadIdx.x, wave = tid >> 6, l = tid & 63;
  int l16 = l & 15, lg = l >> 4;
  int obase = ot * 64;
  f32x4 acc[2][4];
#pragma unroll
  for (int i = 0; i < 2; ++i)
#pragma unroll
    for (int j = 0; j < 4; ++j) acc[i][j] = (f32x4)0.0f;

  // pixel p = wave*32 + mt*16 + (lane part);  p = 2*w + rr  (rr = row within pair)
  for (int cc = 0; cc < 256; cc += 32){
    s16x8 a[2], bf[4];
#pragma unroll
    for (int mt = 0; mt < 2; ++mt){
      int p  = wave*32 + mt*16 + l16;
      int w  = p >> 1, rr = p & 1;
      int hin = rp*2 + rr;
      a[mt] = *(const s16x8*)(Cb + ((b*64 + hin)*64 + w)*512 + 256 + cc + lg*8);
    }
#pragma unroll
    for (int nt = 0; nt < 4; ++nt){
      int o = obase + nt*16 + l16;
      bf[nt] = *(const s16x8*)(cw + o*256 + cc + lg*8);
    }
#pragma unroll
    for (int mt = 0; mt < 2; ++mt)
#pragma unroll
      for (int nt = 0; nt < 4; ++nt)
        acc[mt][nt] = __builtin_amdgcn_mfma_f32_16x16x32_bf16(a[mt], bf[nt], acc[mt][nt], 0, 0, 0);
  }

  // D-frag regs r=0..3 are pixels p0..p0+3 = {(w0,row0),(w0,row1),(w0+1,row0),(w0+1,row1)}
#pragma unroll
  for (int mt = 0; mt < 2; ++mt){
    int j = wave*8 + mt*4 + lg;            // column index in subband
#pragma unroll
    for (int nt = 0; nt < 4; ++nt){
      int o = obase + nt*16 + l16;
      f32x4 v = acc[mt][nt];
      float lo0 = (v.x + v.y)*SQ2, hi0 = (v.x - v.y)*SQ2;
      float lo1 = (v.z + v.w)*SQ2, hi1 = (v.z - v.w)*SQ2;
      float cA = (lo0 + lo1)*SQ2, cV = (lo0 - lo1)*SQ2;
      float cH = (hi0 + hi1)*SQ2, cD = (hi0 - hi1)*SQ2;
      int base = ((b*32 + rp)*32 + j)*256 + o;
      sub[base]              = cA;
      sub[base +   4194304]  = cH;
      sub[base + 2*4194304]  = cV;
      sub[base + 3*4194304]  = cD;
    }
  }
}

// ---------------- per-subband per-channel batch stats ----------------
__global__ __launch_bounds__(256) void k_stats_sub(const float* __restrict__ sub,
                                                   float* __restrict__ statsA){
  int bx = blockIdx.x;                 // 512 = 4s * 16b * 8posgroup
  int pg = bx & 7, b = (bx >> 3) & 15, s = bx >> 7;
  int t = threadIdx.x;
  const float* base = sub + (size_t)(s*16 + b)*262144 + pg*128*256;
  float sum = 0.f, sq = 0.f;
  for (int pos = 0; pos < 128; ++pos){
    float v = base[pos*256 + t];
    sum += v; sq += v*v;
  }
  atomicAdd(&statsA[(s*256 + t)*2],     sum);
  atomicAdd(&statsA[(s*256 + t)*2 + 1], sq);
}

__global__ void k_fin_A(const float* __restrict__ statsA, const float* __restrict__ gamma,
                        const float* __restrict__ beta, float* __restrict__ bnA){
  int t = blockIdx.x*blockDim.x + threadIdx.x;   // 1024 = 4s*256c
  if (t >= 1024) return;
  int c = t & 255;
  const float n = 16384.f;
  float mean = statsA[t*2] / n;
  float var  = statsA[t*2+1] / n - mean*mean;
  float sc = gamma[c] * rsqrtf(var + 1e-5f);
  bnA[t*2]   = sc;
  bnA[t*2+1] = beta[c] - mean*sc;
}

// ---------------- BN + ReLU + IDWT -> Cb NHWC bf16 channels 0..255 ----------------
__global__ __launch_bounds__(256) void k_bn_idwt(const float* __restrict__ sub,
                                                 const float* __restrict__ bnA,
                                                 unsigned short* __restrict__ Cb){
  int bx = blockIdx.x;                 // 512 = 16b * 32i
  int b = bx >> 5, i = bx & 31;
  int c = threadIdx.x;
  float scA = bnA[c*2],              shA = bnA[c*2+1];
  float scH = bnA[(256+c)*2],        shH = bnA[(256+c)*2+1];
  float scV = bnA[(512+c)*2],        shV = bnA[(512+c)*2+1];
  float scD = bnA[(768+c)*2],        shD = bnA[(768+c)*2+1];
  for (int j = 0; j < 32; ++j){
    size_t idx = ((size_t)(b*32 + i)*32 + j)*256 + c;
    float a  = fmaxf(sub[idx]              * scA + shA, 0.f);
    float hh = fmaxf(sub[idx +   4194304]  * scH + shH, 0.f);
    float v  = fmaxf(sub[idx + 2*4194304]  * scV + shV, 0.f);
    float d  = fmaxf(sub[idx + 3*4194304]  * scD + shD, 0.f);
    float lo_e = (a + v)*SQ2, lo_o = (a - v)*SQ2;
    float hi_e = (hh + d)*SQ2, hi_o = (hh - d)*SQ2;
    int h2 = 2*i, w2 = 2*j;
    Cb[((b*64 + h2  )*64 + w2  )*512 + c] = f2bf((lo_e + hi_e)*SQ2);
    Cb[((b*64 + h2  )*64 + w2+1)*512 + c] = f2bf((lo_o + hi_o)*SQ2);
    Cb[((b*64 + h2+1)*64 + w2  )*512 + c] = f2bf((lo_e - hi_e)*SQ2);
    Cb[((b*64 + h2+1)*64 + w2+1)*512 + c] = f2bf((lo_o - hi_o)*SQ2);
  }
}

// ---------------- 3x3 conv, 512->256, implicit GEMM bf16 MFMA ----------------
#define ICP 40   // padded channel-chunk stride (bank-conflict-free b128)
__global__ __launch_bounds__(256) void k_conv3(const unsigned short* __restrict__ Cb,
                                               const unsigned short* __restrict__ Wb,
                                               const float* __restrict__ bias,
                                               float* __restrict__ y){
  __shared__ unsigned short in_l[4*66*ICP];   // [r=4][ci=66][c=32 pad 40]
  __shared__ unsigned short w_l[9*64*ICP];    // [tap][o=64][c=32 pad 40]
  int bx = blockIdx.x;                 // 2048 = 16b * 32rowpair * 4otile
  int ot = bx & 3, hp = (bx >> 2) & 31, b = bx >> 7;
  int h0 = hp*2, obase = ot*64;
  int tid = threadIdx.x, wave = tid >> 6, l = tid & 63;
  int l16 = l & 15, lg = l >> 4;
  f32x4 acc[4][2];
#pragma unroll
  for (int i = 0; i < 4; ++i){ acc[i][0] = (f32x4)0.0f; acc[i][1] = (f32x4)0.0f; }

  for (int cc = 0; cc < 512; cc += 32){
    // stage input rows h0-1 .. h0+2, cols -1..64, 32 channels
    for (int idx = tid; idx < 1056; idx += 256){
      int cg = idx & 3;
      int q  = idx >> 2;          // 0..263
      int ci = q % 66, r = q / 66;
      int hin = h0 - 1 + r, win = ci - 1;
      s16x8 v = (s16x8)0;
      if ((unsigned)hin < 64u && (unsigned)win < 64u)
        v = *(const s16x8*)(Cb + ((b*64 + hin)*64 + win)*512 + cc + cg*8);
      *(s16x8*)(in_l + (r*66 + ci)*ICP + cg*8) = v;
    }
    // stage weights: 9 taps x 64 o x 32 c
    for (int idx = tid; idx < 2304; idx += 256){
      int cg = idx & 3;
      int o  = (idx >> 2) & 63;
      int tap = idx >> 8;
      s16x8 v = *(const s16x8*)(Wb + (size_t)(tap*256 + obase + o)*512 + cc + cg*8);
      *(s16x8*)(w_l + (tap*64 + o)*ICP + cg*8) = v;
    }
    __syncthreads();
#pragma unroll
    for (int tap = 0; tap < 9; ++tap){
      int kh = tap / 3, kw = tap - kh*3;
      s16x8 af[4], bf[2];
#pragma unroll
      for (int mt = 0; mt < 4; ++mt)
        af[mt] = *(const s16x8*)(w_l + (tap*64 + mt*16 + l16)*ICP + lg*8);
#pragma unroll
      for (int nt = 0; nt < 2; ++nt){
        int n = wave*32 + nt*16 + l16;
        int rloc = n >> 6, wloc = n & 63;
        bf[nt] = *(const s16x8*)(in_l + ((rloc + kh)*66 + wloc + kw)*ICP + lg*8);
      }
#pragma unroll
      for (int mt = 0; mt < 4; ++mt)
#pragma unroll
        for (int nt = 0; nt < 2; ++nt)
          acc[mt][nt] = __builtin_amdgcn_mfma_f32_16x16x32_bf16(af[mt], bf[nt], acc[mt][nt], 0, 0, 0);
    }
    __syncthreads();
  }

  // epilogue: y NCHW f32 (+bias), into d_out
#pragma unroll
  for (int mt = 0; mt < 4; ++mt){
#pragma unroll
    for (int nt = 0; nt < 2; ++nt){
      int n = wave*32 + nt*16 + l16;
      int h = h0 + (n >> 6), w = n & 63;
      f32x4 v = acc[mt][nt];
#pragma unroll
      for (int r = 0; r < 4; ++r){
        int o = obase + mt*16 + lg*4 + r;
        y[((b*256 + o)*64 + h)*64 + w] = v[r] + bias[o];
      }
    }
  }
}

// ---------------- final BN stats + apply ----------------
__global__ __launch_bounds__(256) void k_stats_y(const float* __restrict__ y,
                                                 const float* __restrict__ g,
                                                 const float* __restrict__ be,
                                                 float* __restrict__ bnY){
  int o = blockIdx.x;                  // 256
  int t = threadIdx.x;
  float sum = 0.f, sq = 0.f;
  for (int idx = t; idx < 16384; idx += 256){
    int bb = idx >> 10, p4 = idx & 1023;
    f32x4 v = *(const f32x4*)(y + (size_t)(bb*256 + o)*4096 + p4*4);
    sum += v.x + v.y + v.z + v.w;
    sq  += v.x*v.x + v.y*v.y + v.z*v.z + v.w*v.w;
  }
  __shared__ float s1[256], s2[256];
  s1[t] = sum; s2[t] = sq;
  __syncthreads();
  for (int off = 128; off; off >>= 1){
    if (t < off){ s1[t] += s1[t+off]; s2[t] += s2[t+off]; }
    __syncthreads();
  }
  if (t == 0){
    const float n = 65536.f;
    float mean = s1[0] / n;
    float var  = s2[0] / n - mean*mean;
    float sc = g[o] * rsqrtf(var + 1e-5f);
    bnY[o*2]   = sc;
    bnY[o*2+1] = be[o] - mean*sc;
  }
}

__global__ __launch_bounds__(256) void k_bn_out(float* __restrict__ y,
                                                const float* __restrict__ bnY){
  int gI = blockIdx.x*256 + threadIdx.x;   // 4194304 float4's
  int o = (gI >> 10) & 255;
  float sc = bnY[o*2], sh = bnY[o*2+1];
  f32x4 v = ((const f32x4*)y)[gI];
  v.x = fmaxf(v.x*sc + sh, 0.f);
  v.y = fmaxf(v.y*sc + sh, 0.f);
  v.z = fmaxf(v.z*sc + sh, 0.f);
  v.w = fmaxf(v.w*sc + sh, 0.f);
  ((f32x4*)y)[gI] = v;
}

extern "C" void kernel_launch(void* const* d_in, const int* in_sizes, int n_in,
                              void* d_out, int out_size, void* d_ws, size_t ws_size,
                              hipStream_t stream) {
  const float* x       = (const float*)d_in[0];
  const float* conv_w  = (const float*)d_in[1];
  const float* bn_g    = (const float*)d_in[2];
  const float* bn_b    = (const float*)d_in[3];
  const float* convW_w = (const float*)d_in[4];
  const float* convW_b = (const float*)d_in[5];
  const float* bnW_g   = (const float*)d_in[6];
  const float* bnW_b   = (const float*)d_in[7];
  float* out = (float*)d_out;

  unsigned char* base = (unsigned char*)d_ws;
  unsigned short* Cb   = (unsigned short*)base;                          // 64 MiB NHWC bf16 [16][64][64][512]
  unsigned short* cw_b = (unsigned short*)(base + (64u<<20));            // 128 KiB
  unsigned short* Wb   = (unsigned short*)(base + (64u<<20) + (1u<<20)); // 2.25 MiB
  float* statsA        = (float*)(base + (68u<<20));                     // 8 KiB
  float* bnA           = statsA + 2048;
  float* bnY           = bnA + 2048;

  float* sub = out;   // subbands scratch lives in d_out (exactly 64 MiB), overwritten later by conv output

  hipLaunchKernelGGL(k_cvt_cw, dim3(256), dim3(256), 0, stream, conv_w, cw_b);
  hipLaunchKernelGGL(k_cvt_wb, dim3(1152), dim3(256), 0, stream, convW_w, Wb);
  hipLaunchKernelGGL(k_x_nhwc, dim3(1024), dim3(256), 0, stream, x, Cb);
  hipMemsetAsync(statsA, 0, 4*256*2*sizeof(float), stream);
  hipLaunchKernelGGL(k_gemm1_dwt, dim3(2048), dim3(256), 0, stream, Cb, cw_b, sub);
  hipLaunchKernelGGL(k_stats_sub, dim3(512), dim3(256), 0, stream, sub, statsA);
  hipLaunchKernelGGL(k_fin_A, dim3(4), dim3(256), 0, stream, statsA, bn_g, bn_b, bnA);
  hipLaunchKernelGGL(k_bn_idwt, dim3(512), dim3(256), 0, stream, sub, bnA, Cb);
  hipLaunchKernelGGL(k_conv3, dim3(2048), dim3(256), 0, stream, Cb, Wb, convW_b, out);
  hipLaunchKernelGGL(k_stats_y, dim3(256), dim3(256), 0, stream, out, bnW_g, bnW_b, bnY);
  hipLaunchKernelGGL(k_bn_out, dim3(16384), dim3(256), 0, stream, out, bnY);
}